// Round 8
// baseline (464.009 us; speedup 1.0000x reference)
//
#include <hip/hip_runtime.h>
#include <hip/hip_bf16.h>

typedef __hip_bfloat16 bf16;
typedef __attribute__((ext_vector_type(8))) short short8;
typedef __attribute__((ext_vector_type(4))) short short4v;
typedef __attribute__((ext_vector_type(4))) float floatx4;

#define T_SEQ 4096
#define C_DIM 2048
#define NHEAD 16
#define HSZ   128
#define NGRP  4

#define MFMA_BF16(A,B,C) __builtin_amdgcn_mfma_f32_16x16x32_bf16((A),(B),(C),0,0,0)

__device__ __forceinline__ void gld_lds16(const bf16* g, bf16* l) {
  __builtin_amdgcn_global_load_lds(
      (__attribute__((address_space(1))) void*)(g),
      (__attribute__((address_space(3))) void*)(l), 16, 0, 0);
}

// fp32 -> bf16 cast, 8 elements/thread
__global__ void cvt_kernel(const float* __restrict__ src, bf16* __restrict__ dst, long n)
{
  const long i = ((long)blockIdx.x * blockDim.x + threadIdx.x) * 8;
  if (i >= n) return;
  const float4 a = *(const float4*)(src + i);
  const float4 b = *(const float4*)(src + i + 4);
  bf16 tmp[8];
  tmp[0] = __float2bfloat16(a.x); tmp[1] = __float2bfloat16(a.y);
  tmp[2] = __float2bfloat16(a.z); tmp[3] = __float2bfloat16(a.w);
  tmp[4] = __float2bfloat16(b.x); tmp[5] = __float2bfloat16(b.y);
  tmp[6] = __float2bfloat16(b.z); tmp[7] = __float2bfloat16(b.w);
  *(short8*)(dst + i) = *(const short8*)tmp;
}

// C = A (MxK) * B^T (NxK), bf16 in, fp32 accum.
// qkv_mode==1: N=3072, scatter bf16 to Q/K (row-major) and V^T (d-major) buffers.
//              V^T goes through LDS (As reused) so global stores are coalesced.
// qkv_mode==0: fp32 output to Cf with ld = 2048 (proj GEMM).
__global__ __launch_bounds__(256, 3)
void gemm_bt_kernel(const bf16* __restrict__ A, const bf16* __restrict__ B,
                    float* __restrict__ Cf, bf16* __restrict__ Cq,
                    bf16* __restrict__ Ck, bf16* __restrict__ Cvt,
                    int K, int qkv_mode)
{
  __shared__ alignas(16) bf16 As[128 * 64];
  __shared__ alignas(16) bf16 Bs[128 * 64];

  const int t  = threadIdx.x;
  const int w  = t >> 6, l = t & 63;
  const int wr = w >> 1, wc = w & 1;
  const int q4 = l >> 4, ln = l & 15;
  const long bm = (long)blockIdx.y * 128;
  const long bn = (long)blockIdx.x * 128;

  floatx4 acc[4][4] = {};

  const bf16* Ab = A + (bm + t / 8) * (long)K + (t % 8) * 8;
  const bf16* Bb = B + (bn + t / 8) * (long)K + (t % 8) * 8;

  for (int k0 = 0; k0 < K; k0 += 64) {
    __syncthreads();
#pragma unroll
    for (int i = 0; i < 4; ++i) {
      gld_lds16(Ab + (long)i * 32 * K + k0, As + (i * 256 + w * 64) * 8);
      gld_lds16(Bb + (long)i * 32 * K + k0, Bs + (i * 256 + w * 64) * 8);
    }
    __syncthreads();
#pragma unroll
    for (int kk = 0; kk < 64; kk += 32) {
      short8 af[4], bfr[4];
      const int co = kk + q4 * 8;
#pragma unroll
      for (int mi = 0; mi < 4; ++mi)
        af[mi] = *(const short8*)(As + (wr * 64 + mi * 16 + ln) * 64 + co);
#pragma unroll
      for (int ni = 0; ni < 4; ++ni)
        bfr[ni] = *(const short8*)(Bs + (wc * 64 + ni * 16 + ln) * 64 + co);
#pragma unroll
      for (int mi = 0; mi < 4; ++mi)
#pragma unroll
        for (int ni = 0; ni < 4; ++ni)
          acc[mi][ni] = MFMA_BF16(af[mi], bfr[ni], acc[mi][ni]);
    }
  }

  if (!qkv_mode) {
#pragma unroll
    for (int mi = 0; mi < 4; ++mi) {
      const long r0 = bm + wr * 64 + mi * 16 + q4 * 4;
#pragma unroll
      for (int ni = 0; ni < 4; ++ni) {
        const long c = bn + wc * 64 + ni * 16 + ln;
#pragma unroll
        for (int r = 0; r < 4; ++r)
          Cf[(r0 + r) * C_DIM + c] = acc[mi][ni][r];
      }
    }
  } else {
    const int cb = blockIdx.x;
    const int g = cb / 6, slot = cb - g * 6;
    if (slot == 5) {
      // V^T: [d][t] per group. Stage acc into As as [64 d][128 t] (two passes,
      // pass==wc), then store coalesced: 32 t-contiguous elems (64B) per thread,
      // 4 consecutive lanes cover 256 contiguous bytes of one d-row.
      bf16* dstv = Cvt + (long)g * HSZ * T_SEQ;
#pragma unroll
      for (int pass = 0; pass < 2; ++pass) {
        __syncthreads();
        if (wc == pass) {
#pragma unroll
          for (int mi = 0; mi < 4; ++mi) {
            const int tc = wr * 64 + mi * 16 + q4 * 4;      // t within tile
#pragma unroll
            for (int ni = 0; ni < 4; ++ni) {
              const int dr = ni * 16 + ln;                  // d within pass
              short4v pk;
#pragma unroll
              for (int r = 0; r < 4; ++r) {
                bf16 v = __float2bfloat16(acc[mi][ni][r]);
                pk[r] = *(short*)&v;
              }
              *(short4v*)(As + dr * 128 + tc) = pk;
            }
          }
        }
        __syncthreads();
        const int row = t >> 2, ch = (t & 3) * 32;          // 64 d-rows x 128 t
        bf16* gp = dstv + (long)(pass * 64 + row) * T_SEQ + bm + ch;
#pragma unroll
        for (int jj = 0; jj < 4; ++jj)
          *(short8*)(gp + jj * 8) = *(const short8*)(As + row * 128 + ch + jj * 8);
      }
    } else {
      bf16* dst = (slot < 4) ? (Cq + (long)(g * 4 + slot) * T_SEQ * HSZ)
                             : (Ck + (long)g * T_SEQ * HSZ);
#pragma unroll
      for (int mi = 0; mi < 4; ++mi) {
        const long r0 = bm + wr * 64 + mi * 16 + q4 * 4;
#pragma unroll
        for (int ni = 0; ni < 4; ++ni) {
          const long c = wc * 64 + ni * 16 + ln;
#pragma unroll
          for (int r = 0; r < 4; ++r)
            dst[(r0 + r) * HSZ + c] = __float2bfloat16(acc[mi][ni][r]);
        }
      }
    }
  }
}

// In-place RoPE, vectorized: 8 consecutive d per thread (G13).
// Q additionally folded with scale*log2(e) (attention uses exp2).
__global__ void rope_kernel(bf16* __restrict__ Q, bf16* __restrict__ Kb,
                            const float* __restrict__ cs, const float* __restrict__ sn)
{
  const long idx = (long)blockIdx.x * blockDim.x + threadIdx.x;
  const long NQ = (long)NHEAD * T_SEQ * 8;     // 8 d-groups of 8
  bf16* buf; long rem; float qs;
  if (idx < NQ) { buf = Q;  rem = idx;      qs = 0.08838834764831845f * 1.4426950408889634f; }
  else          { buf = Kb; rem = idx - NQ; qs = 1.0f; }
  const int d0 = (int)(rem & 7) * 8;
  const int tt = (int)((rem >> 3) & (T_SEQ - 1));
  const int hh = (int)(rem >> 15);
  const float4 c0 = *(const float4*)(cs + tt * 64 + d0);
  const float4 c1 = *(const float4*)(cs + tt * 64 + d0 + 4);
  const float4 s0 = *(const float4*)(sn + tt * 64 + d0);
  const float4 s1 = *(const float4*)(sn + tt * 64 + d0 + 4);
  float cc[8] = {c0.x,c0.y,c0.z,c0.w,c1.x,c1.y,c1.z,c1.w};
  float ss[8] = {s0.x,s0.y,s0.z,s0.w,s1.x,s1.y,s1.z,s1.w};
  bf16* p = buf + ((long)hh * T_SEQ + tt) * HSZ + d0;
  short8 v1 = *(const short8*)(p);
  short8 v2 = *(const short8*)(p + 64);
  short8 o1, o2;
#pragma unroll
  for (int jj = 0; jj < 8; ++jj) {
    short u1 = v1[jj], u2 = v2[jj];
    const float x1 = __bfloat162float(*(bf16*)&u1);
    const float x2 = __bfloat162float(*(bf16*)&u2);
    bf16 y1 = __float2bfloat16((x1 * cc[jj] - x2 * ss[jj]) * qs);
    bf16 y2 = __float2bfloat16((x2 * cc[jj] + x1 * ss[jj]) * qs);
    o1[jj] = *(short*)&y1; o2[jj] = *(short*)&y2;
  }
  *(short8*)(p)      = o1;
  *(short8*)(p + 64) = o2;
}

// Causal flash attention, GQA 4:1. BQ=128 (4 waves x 32 rows), BKV=64.
// 3-way equal split: per pair (c, 31-c) = 66 KV-units, THREE 22-unit blocks
// (grid 768 = 3 blocks/CU, LDS 3x51.7KB = 155KB <= 160KB, lb(256,3)):
//   c<=10: A: tile c full (direct Y) + tile 31-c [44,64-2c) -> slot0 (len 0 ok)
//          B: tile 31-c [0,22) -> slot1 ; C: tile 31-c [22,44) -> slot2
//   c>=11: A: tile c [0,22) -> slot0 ; B: tile c [22,2c+2) -> slot1 +
//          tile 31-c [0,42-2c) -> slot2 ; C: tile 31-c [42-2c,64-2c) -> slot3
// Every block = exactly 22 units. Segment params computed with BRANCHY
// BLOCK-UNIFORM SCALARS (no runtime-indexed arrays -> no scratch; R7 lesson).
// No max-subtraction -> partials additive; combine adds + normalizes.
__global__ __launch_bounds__(256, 3)
void attn_kernel(const bf16* __restrict__ Qg, const bf16* __restrict__ Kg,
                 const bf16* __restrict__ Vtg, bf16* __restrict__ Y,
                 bf16* __restrict__ Opart, float* __restrict__ Lpart)
{
  __shared__ alignas(16) bf16 Ks[64][132];   // pad 132: kf reads hit 8 dwords/bank (floor)
  __shared__ alignas(16) bf16 Vt[128][68];   // V^T tile [d][s], pad 68
  __shared__ alignas(16) bf16 Ps[128][68];   // P tile, pad 68: scalar writes 32-bank spread

  const int id  = blockIdx.x;                // [0, 768)
  const int h   = id / 48;
  const int r   = id - h * 48;
  const int c   = r / 3;                     // pair index [0,16)
  const int sl  = r - c * 3;                 // 0=A, 1=B, 2=C
  const int g   = h >> 2;

  const bool two = (c <= 10) ? (sl == 0) : (sl == 1);
  const int nph  = two ? 2 : 1;
  const int pairBase = h * 53 + ((c <= 10) ? c * 3 : 33 + (c - 11) * 4);

  const int t = threadIdx.x;
  const int w = t >> 6, l = t & 63;
  const int q4 = l >> 4, ln = l & 15;

  const bf16* Qh = Qg + (long)h * T_SEQ * HSZ;
  const bf16* Kh = Kg + (long)g * T_SEQ * HSZ;
  const bf16* Vh = Vtg + (long)g * HSZ * T_SEQ;   // [d][t]

  // ones B-frag: B[n==0][k] = 1.0 -> MFMA produces row sums in column 0
  short8 ones_f;
#pragma unroll
  for (int i = 0; i < 8; ++i) ones_f[i] = (ln == 0) ? (short)0x3F80 : (short)0;

  // prefetch addressing: K tile row = (t>>4)+16i, col = (t&15)*8
  //                      V tile d   = (t>>3)+32i, col = (t&7)*8
  const int krow = t >> 4, kc = (t & 15) * 8;
  const int vrow = t >> 3, vc = (t & 7) * 8;

  for (int ph = 0; ph < nph; ++ph) {
    // segment params: block-uniform scalars, NO arrays (avoids scratch)
    int P, jlo, jhi, psi;
    bool direct = false;
    if (c <= 10) {
      if (sl == 0) {
        if (ph == 0) { P = c;      jlo = 0;  jhi = 2 * c + 2;  psi = 0; direct = true; }
        else         { P = 31 - c; jlo = 44; jhi = 64 - 2 * c; psi = 0; }
      } else if (sl == 1) { P = 31 - c; jlo = 0;  jhi = 22; psi = 1; }
      else                { P = 31 - c; jlo = 22; jhi = 44; psi = 2; }
    } else {
      if (sl == 0)        { P = c;      jlo = 0;  jhi = 22; psi = 0; }
      else if (sl == 1) {
        if (ph == 0) { P = c;      jlo = 22; jhi = 2 * c + 2;  psi = 1; }
        else         { P = 31 - c; jlo = 0;  jhi = 42 - 2 * c; psi = 2; }
      } else              { P = 31 - c; jlo = 42 - 2 * c; jhi = 64 - 2 * c; psi = 3; }
    }
    const int qbase = P * 128 + w * 32;

    // Q A-frags (Q pre-scaled by scale*log2e in rope_kernel)
    short8 qf[2][4];
#pragma unroll
    for (int mi = 0; mi < 2; ++mi) {
      const long row = qbase + mi * 16 + ln;
#pragma unroll
      for (int ks = 0; ks < 4; ++ks)
        qf[mi][ks] = *(const short8*)(Qh + row * HSZ + ks * 32 + q4 * 8);
    }

    floatx4 acc[2][8] = {};
    floatx4 acc_l[2] = {};

    short8 kpre[4], vpre[4];
    {
      const int sb = jlo * 64;
#pragma unroll
      for (int i = 0; i < 4; ++i) {
        kpre[i] = *(const short8*)(Kh + (long)(sb + krow + 16 * i) * HSZ + kc);
        vpre[i] = *(const short8*)(Vh + (long)(vrow + 32 * i) * T_SEQ + sb + vc);
      }
    }

    for (int j = jlo; j < jhi; ++j) {
      const int s0 = j * 64;
      // stage prefetched regs -> LDS
#pragma unroll
      for (int i = 0; i < 4; ++i) {
        *(short8*)(&Ks[krow + 16 * i][kc]) = kpre[i];
        *(short8*)(&Vt[vrow + 32 * i][vc]) = vpre[i];
      }
      __syncthreads();
      // issue prefetch of tile j+1 (consumed at next loop top — a full tile of slack)
      if (j + 1 < jhi) {
        const int s1 = s0 + 64;
#pragma unroll
        for (int i = 0; i < 4; ++i) {
          kpre[i] = *(const short8*)(Kh + (long)(s1 + krow + 16 * i) * HSZ + kc);
          vpre[i] = *(const short8*)(Vh + (long)(vrow + 32 * i) * T_SEQ + s1 + vc);
        }
      }

      // S = Q K^T (32 rows x 64 cols per wave)
      floatx4 sacc[2][4] = {};
#pragma unroll
      for (int ks = 0; ks < 4; ++ks) {
        short8 kf[4];
#pragma unroll
        for (int ni = 0; ni < 4; ++ni)
          kf[ni] = *(const short8*)(&Ks[ni * 16 + ln][ks * 32 + q4 * 8]);
#pragma unroll
        for (int mi = 0; mi < 2; ++mi)
#pragma unroll
          for (int ni = 0; ni < 4; ++ni)
            sacc[mi][ni] = MFMA_BF16(qf[mi][ks], kf[ni], sacc[mi][ni]);
      }

      // p = exp2(s) with causal zeroing; write to Ps (wave-private rows, no barrier)
#pragma unroll
      for (int mi = 0; mi < 2; ++mi) {
        const int base_m = qbase + mi * 16 + q4 * 4 - s0 - ln;  // keep iff base_m + r - ni*16 >= 0
#pragma unroll
        for (int ni = 0; ni < 4; ++ni)
#pragma unroll
          for (int r2 = 0; r2 < 4; ++r2) {
            float pv = __builtin_amdgcn_exp2f(sacc[mi][ni][r2]);
            if (base_m + r2 - ni * 16 < 0) pv = 0.f;
            Ps[w * 32 + mi * 16 + q4 * 4 + r2][ni * 16 + ln] = __float2bfloat16(pv);
          }
      }

      // O += P V ; l += P * ones
#pragma unroll
      for (int ks = 0; ks < 2; ++ks) {
        short8 pf[2], vf[8];
#pragma unroll
        for (int mi = 0; mi < 2; ++mi)
          pf[mi] = *(const short8*)(&Ps[w * 32 + mi * 16 + ln][ks * 32 + q4 * 8]);
#pragma unroll
        for (int nd = 0; nd < 8; ++nd)
          vf[nd] = *(const short8*)(&Vt[nd * 16 + ln][ks * 32 + q4 * 8]);
#pragma unroll
        for (int mi = 0; mi < 2; ++mi) {
          acc_l[mi] = MFMA_BF16(pf[mi], ones_f, acc_l[mi]);
#pragma unroll
          for (int nd = 0; nd < 8; ++nd)
            acc[mi][nd] = MFMA_BF16(pf[mi], vf[nd], acc[mi][nd]);
        }
      }
      __syncthreads();   // all waves done reading Ks/Vt before next staging write
    }

    if (direct) {
      // epilogue: broadcast l from column-0 lanes, normalize, store Y[t][h*128+d]
#pragma unroll
      for (int mi = 0; mi < 2; ++mi) {
#pragma unroll
        for (int r2 = 0; r2 < 4; ++r2) {
          const float lv = __shfl(acc_l[mi][r2], l & 48, 64);
          const float inv = (lv > 0.f) ? 1.f / lv : 0.f;
          const long tq = qbase + mi * 16 + q4 * 4 + r2;
#pragma unroll
          for (int nd = 0; nd < 8; ++nd)
            Y[tq * C_DIM + h * HSZ + nd * 16 + ln] = __float2bfloat16(acc[mi][nd][r2] * inv);
        }
      }
    } else {
      // partial epilogue: unnormalized O (bf16) + l (fp32), additive across segments
      const int sidx = pairBase + psi;
      bf16* Op = Opart + (long)sidx * (128 * 128);
      float* Lp = Lpart + sidx * 128;
#pragma unroll
      for (int mi = 0; mi < 2; ++mi) {
#pragma unroll
        for (int r2 = 0; r2 < 4; ++r2) {
          const int row = w * 32 + mi * 16 + q4 * 4 + r2;
          if (ln == 0) Lp[row] = acc_l[mi][r2];   // col-0 lanes hold row sums
#pragma unroll
          for (int nd = 0; nd < 8; ++nd)
            Op[row * 128 + nd * 16 + ln] = __float2bfloat16(acc[mi][nd][r2]);
        }
      }
    }
  }
}

// Combine partial KV-segments of split q-tiles: O = (ΣO_k)/(Σl_k), write Y.
// Grid 336 = 16 heads x 21: u<11 -> tile 31-u, 3 slots; u>=11 -> c=11+(u-11)/2,
// even: tile c (slots pb+0,1), odd: tile 31-c (slots pb+2,3).
__global__ void combine_kernel(const bf16* __restrict__ Opart,
                               const float* __restrict__ Lpart,
                               bf16* __restrict__ Y)
{
  const int cid = blockIdx.x;            // [0, 336)
  const int h = cid / 21, u = cid - h * 21;
  int P, sbase, ns;
  if (u < 11) {
    const int c = u; P = 31 - c; sbase = h * 53 + c * 3; ns = 3;
  } else {
    const int v = u - 11;
    const int c = 11 + (v >> 1);
    const int pb = h * 53 + 33 + (c - 11) * 4;
    if (!(v & 1)) { P = c;      sbase = pb;     ns = 2; }
    else          { P = 31 - c; sbase = pb + 2; ns = 2; }
  }
  const long qb = (long)P * 128;
  const int t = threadIdx.x;
#pragma unroll
  for (int it = 0; it < 8; ++it) {
    const int idx = it * 2048 + t * 8;
    const int row = idx >> 7, d = idx & 127;
    float lsum = 0.f;
    float osum[8] = {0.f, 0.f, 0.f, 0.f, 0.f, 0.f, 0.f, 0.f};
    for (int k = 0; k < ns; ++k) {
      lsum += Lpart[(sbase + k) * 128 + row];
      const short8 a = *(const short8*)(Opart + (long)(sbase + k) * 16384 + idx);
#pragma unroll
      for (int jj = 0; jj < 8; ++jj) {
        short ua = a[jj];
        osum[jj] += __bfloat162float(*(bf16*)&ua);
      }
    }
    const float inv = (lsum > 0.f) ? 1.f / lsum : 0.f;
    short8 o;
#pragma unroll
    for (int jj = 0; jj < 8; ++jj) {
      bf16 y = __float2bfloat16(osum[jj] * inv);
      o[jj] = *(short*)&y;
    }
    *(short8*)(Y + (qb + row) * C_DIM + h * HSZ + d) = o;
  }
}

extern "C" void kernel_launch(void* const* d_in, const int* in_sizes, int n_in,
                              void* d_out, int out_size, void* d_ws, size_t ws_size,
                              hipStream_t stream)
{
  const float* x  = (const float*)d_in[0];
  const float* cs = (const float*)d_in[1];
  const float* sn = (const float*)d_in[2];
  const float* Wa = (const float*)d_in[3];
  const float* Wp = (const float*)d_in[4];
  float* out = (float*)d_out;

  const long nx  = (long)T_SEQ * C_DIM;
  const long nwa = (long)(NHEAD + 2 * NGRP) * HSZ * C_DIM;
  const long nwp = (long)C_DIM * C_DIM;
  const long nqh = (long)NHEAD * T_SEQ * HSZ;
  const long nkg = (long)NGRP * T_SEQ * HSZ;

  const size_t need = (size_t)(nx + nwa + nqh + 2 * nkg + nqh) * sizeof(bf16);
  if (ws_size < need) return;

  bf16* xb  = (bf16*)d_ws;  // after QKV GEMM: reused as attn O/l partials
  bf16* Wab = xb + nx;      //   (Opart spans xb+Wab: 848*16384 = 13.89M <= 14.68M)
  bf16* Q   = Wab + nwa;    // after attn: reused for Wp bf16 copy
  bf16* K   = Q + nqh;
  bf16* Vt  = K + nkg;      // V^T: [g][d][t]
  bf16* Y   = Vt + nkg;
  bf16* Wpb = Q;            // Q dead after attn; cvt(Wp) runs after attn (stream order)
  bf16* Opart = xb;                                  // 848 slots x 16384
  float* Lpart = (float*)(xb + 848L * 16384);        // 848 x 128 floats, 4B-aligned

  cvt_kernel<<<(int)(nx  / 8 / 256), 256, 0, stream>>>(x,  xb,  nx);
  cvt_kernel<<<(int)(nwa / 8 / 256), 256, 0, stream>>>(Wa, Wab, nwa);
  gemm_bt_kernel<<<dim3(24, 32), 256, 0, stream>>>(xb, Wab, nullptr, Q, K, Vt, C_DIM, 1);
  rope_kernel<<<2560, 256, 0, stream>>>(Q, K, cs, sn);
  attn_kernel<<<768, 256, 0, stream>>>(Q, K, Vt, Y, Opart, Lpart);
  combine_kernel<<<336, 256, 0, stream>>>(Opart, Lpart, Y);
  cvt_kernel<<<(int)(nwp / 8 / 256), 256, 0, stream>>>(Wp, Wpb, nwp);
  gemm_bt_kernel<<<dim3(16, 32), 256, 0, stream>>>(Y, Wpb, out, nullptr, nullptr, nullptr, C_DIM, 0);
}

// Round 9
// 335.233 us; speedup vs baseline: 1.3841x; 1.3841x over previous
//
#include <hip/hip_runtime.h>
#include <hip/hip_bf16.h>

typedef __hip_bfloat16 bf16;
typedef __attribute__((ext_vector_type(8))) short short8;
typedef __attribute__((ext_vector_type(4))) short short4v;
typedef __attribute__((ext_vector_type(4))) float floatx4;

#define T_SEQ 4096
#define C_DIM 2048
#define NHEAD 16
#define HSZ   128
#define NGRP  4

#define MFMA_BF16(A,B,C) __builtin_amdgcn_mfma_f32_16x16x32_bf16((A),(B),(C),0,0,0)

__device__ __forceinline__ void gld_lds16(const bf16* g, bf16* l) {
  __builtin_amdgcn_global_load_lds(
      (__attribute__((address_space(1))) void*)(g),
      (__attribute__((address_space(3))) void*)(l), 16, 0, 0);
}

// fp32 -> bf16 cast, 8 elements/thread
__global__ void cvt_kernel(const float* __restrict__ src, bf16* __restrict__ dst, long n)
{
  const long i = ((long)blockIdx.x * blockDim.x + threadIdx.x) * 8;
  if (i >= n) return;
  const float4 a = *(const float4*)(src + i);
  const float4 b = *(const float4*)(src + i + 4);
  bf16 tmp[8];
  tmp[0] = __float2bfloat16(a.x); tmp[1] = __float2bfloat16(a.y);
  tmp[2] = __float2bfloat16(a.z); tmp[3] = __float2bfloat16(a.w);
  tmp[4] = __float2bfloat16(b.x); tmp[5] = __float2bfloat16(b.y);
  tmp[6] = __float2bfloat16(b.z); tmp[7] = __float2bfloat16(b.w);
  *(short8*)(dst + i) = *(const short8*)tmp;
}

// C = A (MxK) * B^T (NxK), bf16 in, fp32 accum.
// qkv_mode==1: N=3072. Q/K slots: RoPE FUSED in epilogue (stage bf16 tile to
//              LDS [128][132], barrier, 2 thr/row rotate pairs (d,d+64) in f32,
//              Q additionally scaled by scale*log2e; bit-identical numerics to
//              the old separate rope kernel). V slot: V^T via LDS, coalesced.
// qkv_mode==0: fp32 output to Cf with ld = 2048 (proj GEMM).
__global__ __launch_bounds__(256, 3)
void gemm_bt_kernel(const bf16* __restrict__ A, const bf16* __restrict__ B,
                    float* __restrict__ Cf, bf16* __restrict__ Cq,
                    bf16* __restrict__ Ck, bf16* __restrict__ Cvt,
                    const float* __restrict__ cs, const float* __restrict__ sn,
                    int K, int qkv_mode)
{
  // main loop: As = smem[0:8192) [128][64], Bs = smem[8192:16384) [128][64]
  // Q/K epilogue: Ts = smem as [128][132] (pad 132 -> conflict-free scatter)
  __shared__ alignas(16) bf16 smem[128 * 132];
  bf16* As = smem;
  bf16* Bs = smem + 128 * 64;

  const int t  = threadIdx.x;
  const int w  = t >> 6, l = t & 63;
  const int wr = w >> 1, wc = w & 1;
  const int q4 = l >> 4, ln = l & 15;
  const long bm = (long)blockIdx.y * 128;
  const long bn = (long)blockIdx.x * 128;

  floatx4 acc[4][4] = {};

  const bf16* Ab = A + (bm + t / 8) * (long)K + (t % 8) * 8;
  const bf16* Bb = B + (bn + t / 8) * (long)K + (t % 8) * 8;

  for (int k0 = 0; k0 < K; k0 += 64) {
    __syncthreads();
#pragma unroll
    for (int i = 0; i < 4; ++i) {
      gld_lds16(Ab + (long)i * 32 * K + k0, As + (i * 256 + w * 64) * 8);
      gld_lds16(Bb + (long)i * 32 * K + k0, Bs + (i * 256 + w * 64) * 8);
    }
    __syncthreads();
#pragma unroll
    for (int kk = 0; kk < 64; kk += 32) {
      short8 af[4], bfr[4];
      const int co = kk + q4 * 8;
#pragma unroll
      for (int mi = 0; mi < 4; ++mi)
        af[mi] = *(const short8*)(As + (wr * 64 + mi * 16 + ln) * 64 + co);
#pragma unroll
      for (int ni = 0; ni < 4; ++ni)
        bfr[ni] = *(const short8*)(Bs + (wc * 64 + ni * 16 + ln) * 64 + co);
#pragma unroll
      for (int mi = 0; mi < 4; ++mi)
#pragma unroll
        for (int ni = 0; ni < 4; ++ni)
          acc[mi][ni] = MFMA_BF16(af[mi], bfr[ni], acc[mi][ni]);
    }
  }

  if (!qkv_mode) {
#pragma unroll
    for (int mi = 0; mi < 4; ++mi) {
      const long r0 = bm + wr * 64 + mi * 16 + q4 * 4;
#pragma unroll
      for (int ni = 0; ni < 4; ++ni) {
        const long c = bn + wc * 64 + ni * 16 + ln;
#pragma unroll
        for (int r = 0; r < 4; ++r)
          Cf[(r0 + r) * C_DIM + c] = acc[mi][ni][r];
      }
    }
  } else {
    const int cb = blockIdx.x;
    const int g = cb / 6, slot = cb - g * 6;
    if (slot == 5) {
      // V^T: [d][t] per group. Stage acc into As as [64 d][128 t] (two passes,
      // pass==wc), then store coalesced: 32 t-contiguous elems (64B) per thread,
      // 4 consecutive lanes cover 256 contiguous bytes of one d-row.
      bf16* dstv = Cvt + (long)g * HSZ * T_SEQ;
#pragma unroll
      for (int pass = 0; pass < 2; ++pass) {
        __syncthreads();
        if (wc == pass) {
#pragma unroll
          for (int mi = 0; mi < 4; ++mi) {
            const int tc = wr * 64 + mi * 16 + q4 * 4;      // t within tile
#pragma unroll
            for (int ni = 0; ni < 4; ++ni) {
              const int dr = ni * 16 + ln;                  // d within pass
              short4v pk;
#pragma unroll
              for (int r = 0; r < 4; ++r) {
                bf16 v = __float2bfloat16(acc[mi][ni][r]);
                pk[r] = *(short*)&v;
              }
              *(short4v*)(As + dr * 128 + tc) = pk;
            }
          }
        }
        __syncthreads();
        const int row = t >> 2, ch = (t & 3) * 32;          // 64 d-rows x 128 t
        bf16* gp = dstv + (long)(pass * 64 + row) * T_SEQ + bm + ch;
#pragma unroll
        for (int jj = 0; jj < 4; ++jj)
          *(short8*)(gp + jj * 8) = *(const short8*)(As + row * 128 + ch + jj * 8);
      }
    } else {
      // Q or K with fused RoPE
      bf16* dst = (slot < 4) ? (Cq + (long)(g * 4 + slot) * T_SEQ * HSZ)
                             : (Ck + (long)g * T_SEQ * HSZ);
      const float qs = (slot < 4) ? (0.08838834764831845f * 1.4426950408889634f) : 1.0f;
      __syncthreads();   // all MFMA reads of As/Bs done before Ts overwrite
      bf16* Ts = smem;   // [128][132]
#pragma unroll
      for (int mi = 0; mi < 4; ++mi) {
        const int tl0 = wr * 64 + mi * 16 + q4 * 4;
#pragma unroll
        for (int ni = 0; ni < 4; ++ni) {
          const int cc = wc * 64 + ni * 16 + ln;
#pragma unroll
          for (int r = 0; r < 4; ++r)
            Ts[(tl0 + r) * 132 + cc] = __float2bfloat16(acc[mi][ni][r]);
        }
      }
      __syncthreads();
      // rope: 2 threads per row; thread handles 32 pairs (d, d+64)
      const int tl = t >> 1, d0 = (t & 1) * 32;
      const long trow = bm + tl;
      bf16* gp = dst + trow * HSZ;
#pragma unroll
      for (int dj = 0; dj < 4; ++dj) {
        const int d = d0 + dj * 8;
        const short8 v1 = *(const short8*)(Ts + tl * 132 + d);
        const short8 v2 = *(const short8*)(Ts + tl * 132 + d + 64);
        const float4 c0 = *(const float4*)(cs + trow * 64 + d);
        const float4 c1 = *(const float4*)(cs + trow * 64 + d + 4);
        const float4 s0 = *(const float4*)(sn + trow * 64 + d);
        const float4 s1 = *(const float4*)(sn + trow * 64 + d + 4);
        const float ccv[8] = {c0.x,c0.y,c0.z,c0.w,c1.x,c1.y,c1.z,c1.w};
        const float ssv[8] = {s0.x,s0.y,s0.z,s0.w,s1.x,s1.y,s1.z,s1.w};
        short8 o1, o2;
#pragma unroll
        for (int jj = 0; jj < 8; ++jj) {
          short u1 = v1[jj], u2 = v2[jj];
          const float x1 = __bfloat162float(*(bf16*)&u1);
          const float x2 = __bfloat162float(*(bf16*)&u2);
          bf16 y1 = __float2bfloat16((x1 * ccv[jj] - x2 * ssv[jj]) * qs);
          bf16 y2 = __float2bfloat16((x2 * ccv[jj] + x1 * ssv[jj]) * qs);
          o1[jj] = *(short*)&y1; o2[jj] = *(short*)&y2;
        }
        *(short8*)(gp + d) = o1;
        *(short8*)(gp + d + 64) = o2;
      }
    }
  }
}

// Causal flash attention, GQA 4:1. BQ=128 (4 waves x 32 rows), BKV=64.
// EQUAL-WORK blocks (33 KV-units each), grid 512 = 2 blocks/CU, all retire
// together -> 8 waves/CU sustained. Per head, pair (c, 31-c), c in [0,16):
//   block A: tile c, KV [0, 2c+2)  (direct Y)  THEN tile 31-c, KV [33, 64-2c) (partial)
//   block B: tile 31-c, KV [0, 33)                                            (partial)
// No max-subtraction -> partials (unnormalized O, l) additive over disjoint
// KV ranges; combine kernel adds + normalizes. lb(256,2): DO NOT raise to 3 —
// ~200 regs/wave total => lb(256,3) forces accumulator spill (R7/R8: VGPR 84,
// 600MB scratch traffic, 2x slowdown).
__global__ __launch_bounds__(256, 2)
void attn_kernel(const bf16* __restrict__ Qg, const bf16* __restrict__ Kg,
                 const bf16* __restrict__ Vtg, bf16* __restrict__ Y,
                 bf16* __restrict__ Opart, float* __restrict__ Lpart)
{
  __shared__ alignas(16) bf16 Ks[64][132];   // pad 132: kf reads hit 8 dwords/bank (floor)
  __shared__ alignas(16) bf16 Vt[128][68];   // V^T tile [d][s], pad 68
  __shared__ alignas(16) bf16 Ps[128][68];   // P tile, pad 68: scalar writes 32-bank spread

  const int id  = blockIdx.x;                // [0, 512)
  const int h   = id >> 5;
  const int r   = id & 31;
  const int c   = r >> 1;                    // pair index [0,16)
  const int isA = r & 1;
  const int g   = h >> 2;

  const int t = threadIdx.x;
  const int w = t >> 6, l = t & 63;
  const int q4 = l >> 4, ln = l & 15;

  const bf16* Qh = Qg + (long)h * T_SEQ * HSZ;
  const bf16* Kh = Kg + (long)g * T_SEQ * HSZ;
  const bf16* Vh = Vtg + (long)g * HSZ * T_SEQ;   // [d][t]

  // ones B-frag: B[n==0][k] = 1.0 -> MFMA produces row sums in column 0
  short8 ones_f;
#pragma unroll
  for (int i = 0; i < 8; ++i) ones_f[i] = (ln == 0) ? (short)0x3F80 : (short)0;

  // prefetch addressing: K tile row = (t>>4)+16i, col = (t&15)*8
  //                      V tile d   = (t>>3)+32i, col = (t&7)*8
  const int krow = t >> 4, kc = (t & 15) * 8;
  const int vrow = t >> 3, vc = (t & 7) * 8;

  const int nph = isA ? 2 : 1;
  for (int ph = 0; ph < nph; ++ph) {
    const int P      = (isA && ph == 0) ? c : (31 - c);
    const int jlo    = (isA && ph == 1) ? 33 : 0;
    const int jhi    = isA ? (ph == 0 ? (2 * c + 2) : (64 - 2 * c)) : 33;
    const bool direct = (isA && ph == 0);
    const int qbase  = P * 128 + w * 32;

    // Q A-frags (Q pre-scaled by scale*log2e in the fused-rope GEMM epilogue)
    short8 qf[2][4];
#pragma unroll
    for (int mi = 0; mi < 2; ++mi) {
      const long row = qbase + mi * 16 + ln;
#pragma unroll
      for (int ks = 0; ks < 4; ++ks)
        qf[mi][ks] = *(const short8*)(Qh + row * HSZ + ks * 32 + q4 * 8);
    }

    floatx4 acc[2][8] = {};
    floatx4 acc_l[2] = {};

    short8 kpre[4], vpre[4];
    {
      const int sb = jlo * 64;
#pragma unroll
      for (int i = 0; i < 4; ++i) {
        kpre[i] = *(const short8*)(Kh + (long)(sb + krow + 16 * i) * HSZ + kc);
        vpre[i] = *(const short8*)(Vh + (long)(vrow + 32 * i) * T_SEQ + sb + vc);
      }
    }

    for (int j = jlo; j < jhi; ++j) {
      const int s0 = j * 64;
      // stage prefetched regs -> LDS
#pragma unroll
      for (int i = 0; i < 4; ++i) {
        *(short8*)(&Ks[krow + 16 * i][kc]) = kpre[i];
        *(short8*)(&Vt[vrow + 32 * i][vc]) = vpre[i];
      }
      __syncthreads();
      // issue prefetch of tile j+1 (consumed at next loop top — a full tile of slack)
      if (j + 1 < jhi) {
        const int s1 = s0 + 64;
#pragma unroll
        for (int i = 0; i < 4; ++i) {
          kpre[i] = *(const short8*)(Kh + (long)(s1 + krow + 16 * i) * HSZ + kc);
          vpre[i] = *(const short8*)(Vh + (long)(vrow + 32 * i) * T_SEQ + s1 + vc);
        }
      }

      // S = Q K^T (32 rows x 64 cols per wave)
      floatx4 sacc[2][4] = {};
#pragma unroll
      for (int ks = 0; ks < 4; ++ks) {
        short8 kf[4];
#pragma unroll
        for (int ni = 0; ni < 4; ++ni)
          kf[ni] = *(const short8*)(&Ks[ni * 16 + ln][ks * 32 + q4 * 8]);
#pragma unroll
        for (int mi = 0; mi < 2; ++mi)
#pragma unroll
          for (int ni = 0; ni < 4; ++ni)
            sacc[mi][ni] = MFMA_BF16(qf[mi][ks], kf[ni], sacc[mi][ni]);
      }

      // p = exp2(s) with causal zeroing; write to Ps (wave-private rows, no barrier)
#pragma unroll
      for (int mi = 0; mi < 2; ++mi) {
        const int base_m = qbase + mi * 16 + q4 * 4 - s0 - ln;  // keep iff base_m + r - ni*16 >= 0
#pragma unroll
        for (int ni = 0; ni < 4; ++ni)
#pragma unroll
          for (int r2 = 0; r2 < 4; ++r2) {
            float pv = __builtin_amdgcn_exp2f(sacc[mi][ni][r2]);
            if (base_m + r2 - ni * 16 < 0) pv = 0.f;
            Ps[w * 32 + mi * 16 + q4 * 4 + r2][ni * 16 + ln] = __float2bfloat16(pv);
          }
      }

      // O += P V ; l += P * ones
#pragma unroll
      for (int ks = 0; ks < 2; ++ks) {
        short8 pf[2], vf[8];
#pragma unroll
        for (int mi = 0; mi < 2; ++mi)
          pf[mi] = *(const short8*)(&Ps[w * 32 + mi * 16 + ln][ks * 32 + q4 * 8]);
#pragma unroll
        for (int nd = 0; nd < 8; ++nd)
          vf[nd] = *(const short8*)(&Vt[nd * 16 + ln][ks * 32 + q4 * 8]);
#pragma unroll
        for (int mi = 0; mi < 2; ++mi) {
          acc_l[mi] = MFMA_BF16(pf[mi], ones_f, acc_l[mi]);
#pragma unroll
          for (int nd = 0; nd < 8; ++nd)
            acc[mi][nd] = MFMA_BF16(pf[mi], vf[nd], acc[mi][nd]);
        }
      }
      __syncthreads();   // all waves done reading Ks/Vt before next staging write
    }

    if (direct) {
      // epilogue: broadcast l from column-0 lanes, normalize, store Y[t][h*128+d]
#pragma unroll
      for (int mi = 0; mi < 2; ++mi) {
#pragma unroll
        for (int r2 = 0; r2 < 4; ++r2) {
          const float lv = __shfl(acc_l[mi][r2], l & 48, 64);
          const float inv = (lv > 0.f) ? 1.f / lv : 0.f;
          const long tq = qbase + mi * 16 + q4 * 4 + r2;
#pragma unroll
          for (int nd = 0; nd < 8; ++nd)
            Y[tq * C_DIM + h * HSZ + nd * 16 + ln] = __float2bfloat16(acc[mi][nd][r2] * inv);
        }
      }
    } else {
      // partial epilogue: unnormalized O (bf16) + l (fp32), additive across halves
      const int sidx = (h * 16 + (15 - c)) * 2 + isA;   // B->even, A-tail->odd
      bf16* Op = Opart + (long)sidx * (128 * 128);
      float* Lp = Lpart + sidx * 128;
#pragma unroll
      for (int mi = 0; mi < 2; ++mi) {
#pragma unroll
        for (int r2 = 0; r2 < 4; ++r2) {
          const int row = w * 32 + mi * 16 + q4 * 4 + r2;
          if (ln == 0) Lp[row] = acc_l[mi][r2];   // col-0 lanes hold row sums
#pragma unroll
          for (int nd = 0; nd < 8; ++nd)
            Op[row * 128 + nd * 16 + ln] = __float2bfloat16(acc[mi][nd][r2]);
        }
      }
    }
  }
}

// Combine the two KV-halves of split q-tiles: O = (O0+O1)/(l0+l1), write Y.
__global__ void combine_kernel(const bf16* __restrict__ Opart,
                               const float* __restrict__ Lpart,
                               bf16* __restrict__ Y)
{
  const int b = blockIdx.x;              // b = h*16 + pp, pp = P-16
  const int h = b >> 4, pp = b & 15;
  const bf16* O0 = Opart + (long)b * 2 * 16384;
  const bf16* O1 = O0 + 16384;
  const float* L0 = Lpart + b * 256;
  const float* L1 = L0 + 128;
  const long qb = (long)(pp + 16) * 128;
  const int t = threadIdx.x;
#pragma unroll
  for (int it = 0; it < 8; ++it) {
    const int idx = it * 2048 + t * 8;
    const int row = idx >> 7, d = idx & 127;
    const float lsum = L0[row] + L1[row];
    const float inv = (lsum > 0.f) ? 1.f / lsum : 0.f;
    const short8 a = *(const short8*)(O0 + idx);
    const short8 bb = *(const short8*)(O1 + idx);
    short8 o;
#pragma unroll
    for (int jj = 0; jj < 8; ++jj) {
      short ua = a[jj], ub = bb[jj];
      const float fa = __bfloat162float(*(bf16*)&ua);
      const float fb = __bfloat162float(*(bf16*)&ub);
      bf16 y = __float2bfloat16((fa + fb) * inv);
      o[jj] = *(short*)&y;
    }
    *(short8*)(Y + (qb + row) * C_DIM + h * HSZ + d) = o;
  }
}

extern "C" void kernel_launch(void* const* d_in, const int* in_sizes, int n_in,
                              void* d_out, int out_size, void* d_ws, size_t ws_size,
                              hipStream_t stream)
{
  const float* x  = (const float*)d_in[0];
  const float* cs = (const float*)d_in[1];
  const float* sn = (const float*)d_in[2];
  const float* Wa = (const float*)d_in[3];
  const float* Wp = (const float*)d_in[4];
  float* out = (float*)d_out;

  const long nx  = (long)T_SEQ * C_DIM;
  const long nwa = (long)(NHEAD + 2 * NGRP) * HSZ * C_DIM;
  const long nwp = (long)C_DIM * C_DIM;
  const long nqh = (long)NHEAD * T_SEQ * HSZ;
  const long nkg = (long)NGRP * T_SEQ * HSZ;

  const size_t need = (size_t)(nx + nwa + nqh + 2 * nkg + nqh) * sizeof(bf16);
  if (ws_size < need) return;

  bf16* xb  = (bf16*)d_ws;  // after QKV GEMM: reused as attn O-partials (exact fit)
  bf16* Wab = xb + nx;      // after QKV GEMM: reused as attn l-partials (fp32)
  bf16* Q   = Wab + nwa;    // after attn: reused for Wp bf16 copy
  bf16* K   = Q + nqh;
  bf16* Vt  = K + nkg;      // V^T: [g][d][t]
  bf16* Y   = Vt + nkg;
  bf16* Wpb = Q;            // Q dead after attn; cvt(Wp) runs after attn (stream order)
  bf16* Opart = xb;         // 16*16*2*16384 = 8.39M elems == nx
  float* Lpart = (float*)Wab;  // 65536 floats << nwa

  cvt_kernel<<<(int)(nx  / 8 / 256), 256, 0, stream>>>(x,  xb,  nx);
  cvt_kernel<<<(int)(nwa / 8 / 256), 256, 0, stream>>>(Wa, Wab, nwa);
  gemm_bt_kernel<<<dim3(24, 32), 256, 0, stream>>>(xb, Wab, nullptr, Q, K, Vt, cs, sn, C_DIM, 1);
  attn_kernel<<<512, 256, 0, stream>>>(Q, K, Vt, Y, Opart, Lpart);
  combine_kernel<<<256, 256, 0, stream>>>(Opart, Lpart, Y);
  cvt_kernel<<<(int)(nwp / 8 / 256), 256, 0, stream>>>(Wp, Wpb, nwp);
  gemm_bt_kernel<<<dim3(16, 32), 256, 0, stream>>>(Y, Wpb, out, nullptr, nullptr, nullptr, nullptr, nullptr, C_DIM, 0);
}